// Round 2
// baseline (129.130 us; speedup 1.0000x reference)
//
#include <hip/hip_runtime.h>
#include <math.h>

#define WINDOW 11
#define POLY   3
#define HALF   5
#define EPT    16                 // outputs per thread
#define TPB    256
#define TILE   (EPT * TPB)        // 4096 outputs per block

struct SgCoef {
    float c[WINDOW];          // central FIR taps
    float E[HALF][WINDOW];    // edge fit matrix
};

// ---------------- host-side coefficient computation (double precision) -----

static void invert4(const double M[4][4], double inv[4][4]) {
    double a[4][8];
    for (int i = 0; i < 4; ++i) {
        for (int j = 0; j < 4; ++j) { a[i][j] = M[i][j]; a[i][j + 4] = (i == j) ? 1.0 : 0.0; }
    }
    for (int col = 0; col < 4; ++col) {
        int piv = col;
        for (int r = col + 1; r < 4; ++r)
            if (fabs(a[r][col]) > fabs(a[piv][col])) piv = r;
        if (piv != col)
            for (int j = 0; j < 8; ++j) { double t = a[col][j]; a[col][j] = a[piv][j]; a[piv][j] = t; }
        double d = a[col][col];
        for (int j = 0; j < 8; ++j) a[col][j] /= d;
        for (int r = 0; r < 4; ++r) {
            if (r == col) continue;
            double f = a[r][col];
            for (int j = 0; j < 8; ++j) a[r][j] -= f * a[col][j];
        }
    }
    for (int i = 0; i < 4; ++i)
        for (int j = 0; j < 4; ++j) inv[i][j] = a[i][j + 4];
}

static SgCoef compute_coef() {
    SgCoef co;
    double A[WINDOW][4];
    for (int i = 0; i < WINDOW; ++i) {
        double p = (double)(i - HALF), v = 1.0;
        for (int j = 0; j < 4; ++j) { A[i][j] = v; v *= p; }
    }
    double N[4][4] = {};
    for (int i = 0; i < 4; ++i)
        for (int j = 0; j < 4; ++j) {
            double s = 0;
            for (int r = 0; r < WINDOW; ++r) s += A[r][i] * A[r][j];
            N[i][j] = s;
        }
    double Ninv[4][4];
    invert4(N, Ninv);
    for (int w = 0; w < WINDOW; ++w) {
        double s = 0;
        for (int j = 0; j < 4; ++j) s += Ninv[0][j] * A[w][j];
        co.c[w] = (float)s;
    }
    double V[WINDOW][4];
    for (int i = 0; i < WINDOW; ++i) {
        double p = (double)i, v = 1.0;
        for (int j = 0; j < 4; ++j) { V[i][j] = v; v *= p; }
    }
    double NV[4][4] = {};
    for (int i = 0; i < 4; ++i)
        for (int j = 0; j < 4; ++j) {
            double s = 0;
            for (int r = 0; r < WINDOW; ++r) s += V[r][i] * V[r][j];
            NV[i][j] = s;
        }
    double NVinv[4][4];
    invert4(NV, NVinv);
    for (int h = 0; h < HALF; ++h) {
        double T[4]; double v = 1.0;
        for (int j = 0; j < 4; ++j) { T[j] = v; v *= (double)h; }
        for (int w = 0; w < WINDOW; ++w) {
            double s = 0;
            for (int j = 0; j < 4; ++j) {
                double pv = 0;
                for (int m = 0; m < 4; ++m) pv += NVinv[j][m] * V[w][m];
                s += T[j] * pv;
            }
            co.E[h][w] = (float)s;
        }
    }
    return co;
}

// ---------------- kernel ---------------------------------------------------
// No LDS, no barrier. Each thread: 8x float4 loads -> 32-float register
// window -> 16 outputs -> 4x float4 stores. Halo overlap (2x instruction
// redundancy) is served by L1; HBM bytes are unchanged.

__global__ __launch_bounds__(TPB) void savgol_reg_kernel(
    const float* __restrict__ x, float* __restrict__ out,
    SgCoef coef, int L, int tiles_per_row)
{
    const int t    = threadIdx.x;
    const int tile = blockIdx.x;
    const int row  = blockIdx.y;
    const long long rowoff = (long long)row * (long long)L;
    const float* __restrict__ xr   = x + rowoff;
    float* __restrict__       outr = out + rowoff;

    const int s    = tile * TILE;
    const int base = s + EPT * t - 8;     // first staged element (multiple of 4)

    float v[32];
    const bool oob_lo = (base < 0);              // only t==0 of tile 0
    const bool oob_hi = (base + 31 >= L);        // only t==TPB-1 of last tile

    if (!oob_lo && !oob_hi) {
        const float4* p = reinterpret_cast<const float4*>(xr + base);
        #pragma unroll
        for (int i = 0; i < 8; ++i) {
            float4 q = p[i];
            v[4 * i + 0] = q.x; v[4 * i + 1] = q.y;
            v[4 * i + 2] = q.z; v[4 * i + 3] = q.w;
        }
    } else {
        #pragma unroll
        for (int i = 0; i < 32; ++i) {
            int g = base + i;
            g = g < 0 ? 0 : (g > L - 1 ? L - 1 : g);
            v[i] = xr[g];
        }
    }

    // Interior FIR: out[n] = sum_k c[k] * x[n-5+k]; reg idx of x[n-5+k] = j+3+k
    float o[EPT];
    #pragma unroll
    for (int j = 0; j < EPT; ++j) {
        float acc = 0.0f;
        #pragma unroll
        for (int k = 0; k < WINDOW; ++k)
            acc = fmaf(coef.c[k], v[j + 3 + k], acc);
        o[j] = acc;
    }

    // Left edge: outputs 0..4 live entirely in thread 0 of tile 0
    // (x[w] is at reg w+8).
    if (tile == 0 && t == 0) {
        #pragma unroll
        for (int h = 0; h < HALF; ++h) {
            float a = 0.0f;
            #pragma unroll
            for (int w = 0; w < WINDOW; ++w)
                a = fmaf(coef.E[h][w], v[w + 8], a);
            o[h] = a;
        }
    }
    // Right edge: outputs L-5..L-1 live in thread TPB-1 of the last tile
    // (x[L-1-w] is at reg 23-w).
    if (tile == tiles_per_row - 1 && t == TPB - 1) {
        #pragma unroll
        for (int j = EPT - HALF; j < EPT; ++j) {
            const int h = (EPT - 1) - j;        // = L-1-n for this thread
            float a = 0.0f;
            #pragma unroll
            for (int w = 0; w < WINDOW; ++w)
                a = fmaf(coef.E[h][w], v[23 - w], a);
            o[j] = a;
        }
    }

    float4* po = reinterpret_cast<float4*>(outr + s + EPT * t);
    #pragma unroll
    for (int q = 0; q < 4; ++q)
        po[q] = make_float4(o[4 * q], o[4 * q + 1], o[4 * q + 2], o[4 * q + 3]);
}

// ---------------- launch ---------------------------------------------------

extern "C" void kernel_launch(void* const* d_in, const int* in_sizes, int n_in,
                              void* d_out, int out_size, void* d_ws, size_t ws_size,
                              hipStream_t stream) {
    (void)d_ws; (void)ws_size; (void)n_in; (void)out_size;
    const float* x = (const float*)d_in[0];
    float* out = (float*)d_out;

    const int L = 65536;
    const int rows = in_sizes[0] / L;          // 64*16 = 1024
    const int tiles_per_row = L / TILE;        // 16

    SgCoef coef = compute_coef();

    dim3 grid(tiles_per_row, rows);
    dim3 block(TPB);
    savgol_reg_kernel<<<grid, block, 0, stream>>>(x, out, coef, L, tiles_per_row);
}

// Round 3
// 107.765 us; speedup vs baseline: 1.1983x; 1.1983x over previous
//
#include <hip/hip_runtime.h>
#include <math.h>

#define WINDOW 11
#define POLY   3
#define HALF   5
#define TPB    256
#define TILE   2048               // outputs per block
#define OPT    4                  // consecutive outputs per thread per j-iter
#define NJ     (TILE / (TPB * OPT))   // 2 j-iterations

struct SgCoef {
    float c[WINDOW];          // central FIR taps
    float E[HALF][WINDOW];    // edge fit matrix
};

// ---------------- host-side coefficient computation (double precision) -----

static void invert4(const double M[4][4], double inv[4][4]) {
    double a[4][8];
    for (int i = 0; i < 4; ++i) {
        for (int j = 0; j < 4; ++j) { a[i][j] = M[i][j]; a[i][j + 4] = (i == j) ? 1.0 : 0.0; }
    }
    for (int col = 0; col < 4; ++col) {
        int piv = col;
        for (int r = col + 1; r < 4; ++r)
            if (fabs(a[r][col]) > fabs(a[piv][col])) piv = r;
        if (piv != col)
            for (int j = 0; j < 8; ++j) { double t = a[col][j]; a[col][j] = a[piv][j]; a[piv][j] = t; }
        double d = a[col][col];
        for (int j = 0; j < 8; ++j) a[col][j] /= d;
        for (int r = 0; r < 4; ++r) {
            if (r == col) continue;
            double f = a[r][col];
            for (int j = 0; j < 8; ++j) a[r][j] -= f * a[col][j];
        }
    }
    for (int i = 0; i < 4; ++i)
        for (int j = 0; j < 4; ++j) inv[i][j] = a[i][j + 4];
}

static SgCoef compute_coef() {
    SgCoef co;
    double A[WINDOW][4];
    for (int i = 0; i < WINDOW; ++i) {
        double p = (double)(i - HALF), v = 1.0;
        for (int j = 0; j < 4; ++j) { A[i][j] = v; v *= p; }
    }
    double N[4][4] = {};
    for (int i = 0; i < 4; ++i)
        for (int j = 0; j < 4; ++j) {
            double s = 0;
            for (int r = 0; r < WINDOW; ++r) s += A[r][i] * A[r][j];
            N[i][j] = s;
        }
    double Ninv[4][4];
    invert4(N, Ninv);
    for (int w = 0; w < WINDOW; ++w) {
        double s = 0;
        for (int j = 0; j < 4; ++j) s += Ninv[0][j] * A[w][j];
        co.c[w] = (float)s;
    }
    double V[WINDOW][4];
    for (int i = 0; i < WINDOW; ++i) {
        double p = (double)i, v = 1.0;
        for (int j = 0; j < 4; ++j) { V[i][j] = v; v *= p; }
    }
    double NV[4][4] = {};
    for (int i = 0; i < 4; ++i)
        for (int j = 0; j < 4; ++j) {
            double s = 0;
            for (int r = 0; r < WINDOW; ++r) s += V[r][i] * V[r][j];
            NV[i][j] = s;
        }
    double NVinv[4][4];
    invert4(NV, NVinv);
    for (int h = 0; h < HALF; ++h) {
        double T[4]; double v = 1.0;
        for (int j = 0; j < 4; ++j) { T[j] = v; v *= (double)h; }
        for (int w = 0; w < WINDOW; ++w) {
            double s = 0;
            for (int j = 0; j < 4; ++j) {
                double pv = 0;
                for (int m = 0; m < 4; ++m) pv += NVinv[j][m] * V[w][m];
                s += T[j] * pv;
            }
            co.E[h][w] = (float)s;
        }
    }
    return co;
}

// ---------------- kernel ---------------------------------------------------
// Staging identical to the 97.7us version (coalesced float4 -> LDS).
// Compute side vectorized: each thread does 4 consecutive outputs per j-iter
// via 5x ds_read_b128 (lane stride 16B = conflict-free) and one float4 store.

__global__ __launch_bounds__(TPB) void savgol_kernel(
    const float* __restrict__ x, float* __restrict__ out,
    SgCoef coef, int L, int tiles_per_row)
{
    __shared__ float lds[TILE + 16];   // lds[m+8] = x[s+m],  m in [-8, TILE+8)

    const int t    = threadIdx.x;
    const int tile = blockIdx.x;
    const int row  = blockIdx.y;
    const long long rowoff = (long long)row * (long long)L;
    const int s = tile * TILE;
    const float* __restrict__ xr   = x + rowoff;
    float* __restrict__       outr = out + rowoff;

    // ---- Stage [s-8, s+TILE+8) into LDS with coalesced float4 loads ----
    const int NCHUNK = (TILE + 16) / 4;   // 516
    for (int chunk = t; chunk < NCHUNK; chunk += TPB) {
        int gbase = s - 8 + chunk * 4;
        float4 v;
        if (gbase >= 0 && gbase + 3 < L) {
            v = *reinterpret_cast<const float4*>(xr + gbase);
        } else {
            float vv[4];
            #pragma unroll
            for (int q = 0; q < 4; ++q) {
                int g = gbase + q;
                vv[q] = (g >= 0 && g < L) ? xr[g] : 0.0f;
            }
            v = make_float4(vv[0], vv[1], vv[2], vv[3]);
        }
        *reinterpret_cast<float4*>(&lds[chunk * 4]) = v;
    }
    __syncthreads();

    const bool first = (tile == 0);
    const bool last  = (tile == tiles_per_row - 1);

    #pragma unroll
    for (int j = 0; j < NJ; ++j) {
        const int nl = j * (TPB * OPT) + OPT * t;   // 0..TILE-4, multiple of 4
        // Outputs n = s+nl .. s+nl+3 need lds[nl+3 .. nl+16].
        // 5 aligned ds_read_b128 cover lds[nl .. nl+19].
        float w[20];
        const float4* lp = reinterpret_cast<const float4*>(&lds[nl]);
        #pragma unroll
        for (int q = 0; q < 5; ++q) {
            float4 r = lp[q];
            w[4 * q + 0] = r.x; w[4 * q + 1] = r.y;
            w[4 * q + 2] = r.z; w[4 * q + 3] = r.w;
        }

        float o[OPT];
        #pragma unroll
        for (int idx = 0; idx < OPT; ++idx) {
            float acc = 0.0f;
            #pragma unroll
            for (int k = 0; k < WINDOW; ++k)
                acc = fmaf(coef.c[k], w[idx + 3 + k], acc);
            o[idx] = acc;
        }

        if (first && nl < HALF) {
            // Left edge: out[n] (n<5) = sum_w E[n][w] * x[w];  x[w] = lds[w+8]
            #pragma unroll
            for (int idx = 0; idx < OPT; ++idx) {
                int n = nl + idx;
                if (n < HALF) {
                    float a = 0.0f;
                    #pragma unroll
                    for (int ww = 0; ww < WINDOW; ++ww)
                        a = fmaf(coef.E[n][ww], lds[ww + 8], a);
                    o[idx] = a;
                }
            }
        }
        if (last && nl + OPT - 1 >= TILE - HALF) {
            // Right edge: h = L-1-n; x[L-1-w] = lds[2055 - w]  (s = L-TILE)
            #pragma unroll
            for (int idx = 0; idx < OPT; ++idx) {
                int n = s + nl + idx;
                int h = (L - 1) - n;
                if (h < HALF) {
                    float a = 0.0f;
                    #pragma unroll
                    for (int ww = 0; ww < WINDOW; ++ww)
                        a = fmaf(coef.E[h][ww], lds[(TILE + 7) - ww], a);
                    o[idx] = a;
                }
            }
        }

        *reinterpret_cast<float4*>(outr + s + nl) =
            make_float4(o[0], o[1], o[2], o[3]);
    }
}

// ---------------- launch ---------------------------------------------------

extern "C" void kernel_launch(void* const* d_in, const int* in_sizes, int n_in,
                              void* d_out, int out_size, void* d_ws, size_t ws_size,
                              hipStream_t stream) {
    (void)d_ws; (void)ws_size; (void)n_in; (void)out_size;
    const float* x = (const float*)d_in[0];
    float* out = (float*)d_out;

    const int L = 65536;
    const int rows = in_sizes[0] / L;          // 64*16 = 1024
    const int tiles_per_row = L / TILE;        // 32

    SgCoef coef = compute_coef();

    dim3 grid(tiles_per_row, rows);
    dim3 block(TPB);
    savgol_kernel<<<grid, block, 0, stream>>>(x, out, coef, L, tiles_per_row);
}

// Round 4
// 107.344 us; speedup vs baseline: 1.2030x; 1.0039x over previous
//
#include <hip/hip_runtime.h>
#include <math.h>

#define WINDOW 11
#define POLY   3
#define HALF   5
#define TPB    256
#define OPT    4                    // consecutive outputs per thread per j-iter
#define NJ     2
#define TILE   (TPB * OPT * NJ)     // 2048 outputs per block

struct SgCoef {
    float c[WINDOW];          // central FIR taps
    float E[HALF][WINDOW];    // edge fit matrix
};

// ---------------- host-side coefficient computation (double precision) -----

static void invert4(const double M[4][4], double inv[4][4]) {
    double a[4][8];
    for (int i = 0; i < 4; ++i) {
        for (int j = 0; j < 4; ++j) { a[i][j] = M[i][j]; a[i][j + 4] = (i == j) ? 1.0 : 0.0; }
    }
    for (int col = 0; col < 4; ++col) {
        int piv = col;
        for (int r = col + 1; r < 4; ++r)
            if (fabs(a[r][col]) > fabs(a[piv][col])) piv = r;
        if (piv != col)
            for (int j = 0; j < 8; ++j) { double t = a[col][j]; a[col][j] = a[piv][j]; a[piv][j] = t; }
        double d = a[col][col];
        for (int j = 0; j < 8; ++j) a[col][j] /= d;
        for (int r = 0; r < 4; ++r) {
            if (r == col) continue;
            double f = a[r][col];
            for (int j = 0; j < 8; ++j) a[r][j] -= f * a[col][j];
        }
    }
    for (int i = 0; i < 4; ++i)
        for (int j = 0; j < 4; ++j) inv[i][j] = a[i][j + 4];
}

static SgCoef compute_coef() {
    SgCoef co;
    double A[WINDOW][4];
    for (int i = 0; i < WINDOW; ++i) {
        double p = (double)(i - HALF), v = 1.0;
        for (int j = 0; j < 4; ++j) { A[i][j] = v; v *= p; }
    }
    double N[4][4] = {};
    for (int i = 0; i < 4; ++i)
        for (int j = 0; j < 4; ++j) {
            double s = 0;
            for (int r = 0; r < WINDOW; ++r) s += A[r][i] * A[r][j];
            N[i][j] = s;
        }
    double Ninv[4][4];
    invert4(N, Ninv);
    for (int w = 0; w < WINDOW; ++w) {
        double s = 0;
        for (int j = 0; j < 4; ++j) s += Ninv[0][j] * A[w][j];
        co.c[w] = (float)s;
    }
    double V[WINDOW][4];
    for (int i = 0; i < WINDOW; ++i) {
        double p = (double)i, v = 1.0;
        for (int j = 0; j < 4; ++j) { V[i][j] = v; v *= p; }
    }
    double NV[4][4] = {};
    for (int i = 0; i < 4; ++i)
        for (int j = 0; j < 4; ++j) {
            double s = 0;
            for (int r = 0; r < WINDOW; ++r) s += V[r][i] * V[r][j];
            NV[i][j] = s;
        }
    double NVinv[4][4];
    invert4(NV, NVinv);
    for (int h = 0; h < HALF; ++h) {
        double T[4]; double v = 1.0;
        for (int j = 0; j < 4; ++j) { T[j] = v; v *= (double)h; }
        for (int w = 0; w < WINDOW; ++w) {
            double s = 0;
            for (int j = 0; j < 4; ++j) {
                double pv = 0;
                for (int m = 0; m < 4; ++m) pv += NVinv[j][m] * V[w][m];
                s += T[j] * pv;
            }
            co.E[h][w] = (float)s;
        }
    }
    return co;
}

// ---------------- kernel ---------------------------------------------------
// No LDS, no barrier, no cross-lane ops. Each thread: 4 consecutive outputs
// per j-iter. Window [n-8, n+11] loaded as 5 overlapping dwordx4 with 16B
// lane stride (each load instr = contiguous 1KB/wave). L1 absorbs the 5x
// instruction overlap; HBM traffic stays 1x. float4 coalesced store.

__global__ __launch_bounds__(TPB) void savgol_kernel(
    const float* __restrict__ x, float* __restrict__ out,
    SgCoef coef, int L, int tiles_per_row)
{
    const int t    = threadIdx.x;
    const int tile = blockIdx.x;
    const int row  = blockIdx.y;
    const long long rowoff = (long long)row * (long long)L;
    const float* __restrict__ xr   = x + rowoff;
    float* __restrict__       outr = out + rowoff;
    const int s = tile * TILE;
    const bool first = (tile == 0);
    const bool last  = (tile == tiles_per_row - 1);

    #pragma unroll
    for (int j = 0; j < NJ; ++j) {
        const int n = s + j * (TPB * OPT) + OPT * t;   // first of 4 outputs

        // ---- load window w[m] = x[n-8+m], m=0..19 ----
        float w[20];
        const bool lo = first && (j == 0) && (t < 2);            // n-8 < 0
        const bool hi = last && (j == NJ - 1) && (t >= TPB - 2); // n+11 > L-1
        if (lo || hi) {
            #pragma unroll
            for (int m = 0; m < 20; ++m) {
                int g = n - 8 + m;
                g = g < 0 ? 0 : (g > L - 1 ? L - 1 : g);
                w[m] = xr[g];   // clamped values only feed outputs that get
                                // overwritten by the edge formulas below
            }
        } else {
            const float4* p = reinterpret_cast<const float4*>(xr + n - 8);
            #pragma unroll
            for (int q = 0; q < 5; ++q) {
                float4 r = p[q];
                w[4 * q + 0] = r.x; w[4 * q + 1] = r.y;
                w[4 * q + 2] = r.z; w[4 * q + 3] = r.w;
            }
        }

        // ---- interior FIR: out[n+idx] = sum_k c[k]*x[n+idx-5+k] ----
        float o[OPT];
        #pragma unroll
        for (int idx = 0; idx < OPT; ++idx) {
            float a = 0.0f;
            #pragma unroll
            for (int k = 0; k < WINDOW; ++k)
                a = fmaf(coef.c[k], w[idx + 3 + k], a);
            o[idx] = a;
        }

        // ---- edge overwrites (all-static indices; direct global reads) ----
        if (first && j == 0 && t == 0) {            // outputs 0..3 -> h=0..3
            #pragma unroll
            for (int h = 0; h < 4; ++h) {
                float a = 0.0f;
                #pragma unroll
                for (int ww = 0; ww < WINDOW; ++ww)
                    a = fmaf(coef.E[h][ww], xr[ww], a);
                o[h] = a;
            }
        }
        if (first && j == 0 && t == 1) {            // output 4 -> h=4
            float a = 0.0f;
            #pragma unroll
            for (int ww = 0; ww < WINDOW; ++ww)
                a = fmaf(coef.E[4][ww], xr[ww], a);
            o[0] = a;
        }
        if (last && j == NJ - 1 && t == TPB - 1) {  // outputs L-4..L-1 -> h=3..0
            #pragma unroll
            for (int idx = 0; idx < OPT; ++idx) {
                const int h = 3 - idx;
                float a = 0.0f;
                #pragma unroll
                for (int ww = 0; ww < WINDOW; ++ww)
                    a = fmaf(coef.E[h][ww], xr[(L - 1) - ww], a);
                o[idx] = a;
            }
        }
        if (last && j == NJ - 1 && t == TPB - 2) {  // output L-5 -> h=4
            float a = 0.0f;
            #pragma unroll
            for (int ww = 0; ww < WINDOW; ++ww)
                a = fmaf(coef.E[4][ww], xr[(L - 1) - ww], a);
            o[3] = a;
        }

        *reinterpret_cast<float4*>(outr + n) =
            make_float4(o[0], o[1], o[2], o[3]);
    }
}

// ---------------- launch ---------------------------------------------------

extern "C" void kernel_launch(void* const* d_in, const int* in_sizes, int n_in,
                              void* d_out, int out_size, void* d_ws, size_t ws_size,
                              hipStream_t stream) {
    (void)d_ws; (void)ws_size; (void)n_in; (void)out_size;
    const float* x = (const float*)d_in[0];
    float* out = (float*)d_out;

    const int L = 65536;
    const int rows = in_sizes[0] / L;          // 64*16 = 1024
    const int tiles_per_row = L / TILE;        // 32

    SgCoef coef = compute_coef();

    dim3 grid(tiles_per_row, rows);
    dim3 block(TPB);
    savgol_kernel<<<grid, block, 0, stream>>>(x, out, coef, L, tiles_per_row);
}

// Round 6
// 93.132 us; speedup vs baseline: 1.3865x; 1.1526x over previous
//
#include <hip/hip_runtime.h>
#include <math.h>

#define WINDOW 11
#define POLY   3
#define HALF   5
#define TILE   2048
#define TPB    256
#define EPT    8   // elements per thread = TILE / TPB

typedef float f32x4 __attribute__((ext_vector_type(4)));

struct SgCoef {
    float c[WINDOW];          // central FIR taps
    float E[HALF][WINDOW];    // edge fit matrix
};

// ---------------- host-side coefficient computation (double precision) -----

static void invert4(const double M[4][4], double inv[4][4]) {
    double a[4][8];
    for (int i = 0; i < 4; ++i) {
        for (int j = 0; j < 4; ++j) { a[i][j] = M[i][j]; a[i][j + 4] = (i == j) ? 1.0 : 0.0; }
    }
    for (int col = 0; col < 4; ++col) {
        int piv = col;
        for (int r = col + 1; r < 4; ++r)
            if (fabs(a[r][col]) > fabs(a[piv][col])) piv = r;
        if (piv != col)
            for (int j = 0; j < 8; ++j) { double t = a[col][j]; a[col][j] = a[piv][j]; a[piv][j] = t; }
        double d = a[col][col];
        for (int j = 0; j < 8; ++j) a[col][j] /= d;
        for (int r = 0; r < 4; ++r) {
            if (r == col) continue;
            double f = a[r][col];
            for (int j = 0; j < 8; ++j) a[r][j] -= f * a[col][j];
        }
    }
    for (int i = 0; i < 4; ++i)
        for (int j = 0; j < 4; ++j) inv[i][j] = a[i][j + 4];
}

static SgCoef compute_coef() {
    SgCoef co;
    double A[WINDOW][4];
    for (int i = 0; i < WINDOW; ++i) {
        double p = (double)(i - HALF), v = 1.0;
        for (int j = 0; j < 4; ++j) { A[i][j] = v; v *= p; }
    }
    double N[4][4] = {};
    for (int i = 0; i < 4; ++i)
        for (int j = 0; j < 4; ++j) {
            double s = 0;
            for (int r = 0; r < WINDOW; ++r) s += A[r][i] * A[r][j];
            N[i][j] = s;
        }
    double Ninv[4][4];
    invert4(N, Ninv);
    for (int w = 0; w < WINDOW; ++w) {
        double s = 0;
        for (int j = 0; j < 4; ++j) s += Ninv[0][j] * A[w][j];
        co.c[w] = (float)s;
    }
    double V[WINDOW][4];
    for (int i = 0; i < WINDOW; ++i) {
        double p = (double)i, v = 1.0;
        for (int j = 0; j < 4; ++j) { V[i][j] = v; v *= p; }
    }
    double NV[4][4] = {};
    for (int i = 0; i < 4; ++i)
        for (int j = 0; j < 4; ++j) {
            double s = 0;
            for (int r = 0; r < WINDOW; ++r) s += V[r][i] * V[r][j];
            NV[i][j] = s;
        }
    double NVinv[4][4];
    invert4(NV, NVinv);
    for (int h = 0; h < HALF; ++h) {
        double T[4]; double v = 1.0;
        for (int j = 0; j < 4; ++j) { T[j] = v; v *= (double)h; }
        for (int w = 0; w < WINDOW; ++w) {
            double s = 0;
            for (int j = 0; j < 4; ++j) {
                double pv = 0;
                for (int m = 0; m < 4; ++m) pv += NVinv[j][m] * V[w][m];
                s += T[j] * pv;
            }
            co.E[h][w] = (float)s;
        }
    }
    return co;
}

// ---------------- kernel ---------------------------------------------------
// Identical structure to the 97.7us version (coalesced float4 -> LDS staging,
// stride-TPB scalar outputs). Single change: nontemporal (nt) hints on the
// streaming loads and stores so the touch-once streams don't allocate in
// L2/L3 (537MB working set > 256MB L3; stores otherwise evict the input).
// nt builtins need native vector types -> f32x4 (ext_vector_type).

__global__ __launch_bounds__(TPB) void savgol_kernel(
    const float* __restrict__ x, float* __restrict__ out,
    SgCoef coef, int L, int tiles_per_row)
{
    __shared__ float lds[TILE + 16];   // covers [s-8, s+TILE+8)

    const int t    = threadIdx.x;
    const int tile = blockIdx.x;
    const int row  = blockIdx.y;
    const long long rowoff = (long long)row * (long long)L;
    const int s = tile * TILE;
    const float* __restrict__ xr  = x + rowoff;
    float* __restrict__       outr = out + rowoff;

    // Stage [s-8, s+TILE+8) into LDS with f32x4 nt loads (16B-aligned).
    const int NCHUNK = (TILE + 16) / 4;   // 516
    for (int chunk = t; chunk < NCHUNK; chunk += TPB) {
        int gbase = s - 8 + chunk * 4;
        f32x4 v;
        if (gbase >= 0 && gbase + 3 < L) {
            v = __builtin_nontemporal_load(
                    reinterpret_cast<const f32x4*>(xr + gbase));
        } else {
            #pragma unroll
            for (int q = 0; q < 4; ++q) {
                int g = gbase + q;
                v[q] = (g >= 0 && g < L) ? xr[g] : 0.0f;
            }
        }
        *reinterpret_cast<f32x4*>(&lds[chunk * 4]) = v;
    }
    __syncthreads();

    const bool first = (tile == 0);
    const bool last  = (tile == tiles_per_row - 1);

    #pragma unroll
    for (int j = 0; j < EPT; ++j) {
        const int nl = t + j * TPB;       // 0..TILE-1
        const int n  = s + nl;            // global output index in row
        // Interior FIR: out[n] = sum_k c[k] * x[n-5+k]; lds idx of x[n-5] = nl+3
        float acc = 0.0f;
        #pragma unroll
        for (int k = 0; k < WINDOW; ++k)
            acc = fmaf(coef.c[k], lds[nl + 3 + k], acc);
        float val = acc;
        if (first && nl < HALF) {
            // Left edge: out[h] = sum_w E[h][w] * x[w]; lds idx of x[w] = w+8
            float a = 0.0f;
            #pragma unroll
            for (int w = 0; w < WINDOW; ++w)
                a = fmaf(coef.E[nl][w], lds[w + 8], a);
            val = a;
        } else if (last && nl >= TILE - HALF) {
            // Right edge: h = L-1-n; out[n] = sum_w E[h][w] * x[L-1-w]
            int h = (L - 1) - n;          // 0..4
            float a = 0.0f;
            #pragma unroll
            for (int w = 0; w < WINDOW; ++w)
                a = fmaf(coef.E[h][w], lds[(TILE + 7) - w], a);  // (L-1-w)-(s-8), s=L-TILE
            val = a;
        }
        __builtin_nontemporal_store(val, &outr[n]);
    }
}

// ---------------- launch ---------------------------------------------------

extern "C" void kernel_launch(void* const* d_in, const int* in_sizes, int n_in,
                              void* d_out, int out_size, void* d_ws, size_t ws_size,
                              hipStream_t stream) {
    (void)d_ws; (void)ws_size; (void)n_in; (void)out_size;
    const float* x = (const float*)d_in[0];
    float* out = (float*)d_out;

    const int L = 65536;
    const int rows = in_sizes[0] / L;          // 64*16 = 1024
    const int tiles_per_row = L / TILE;        // 32

    SgCoef coef = compute_coef();

    dim3 grid(tiles_per_row, rows);
    dim3 block(TPB);
    savgol_kernel<<<grid, block, 0, stream>>>(x, out, coef, L, tiles_per_row);
}

// Round 7
// 92.766 us; speedup vs baseline: 1.3920x; 1.0040x over previous
//
#include <hip/hip_runtime.h>
#include <math.h>

#define WINDOW 11
#define POLY   3
#define HALF   5
#define TILE   4096
#define TPB    256
#define EPT    16   // elements per thread = TILE / TPB

typedef float f32x4 __attribute__((ext_vector_type(4)));

struct SgCoef {
    float c[WINDOW];          // central FIR taps
    float E[HALF][WINDOW];    // edge fit matrix
};

// ---------------- host-side coefficient computation (double precision) -----

static void invert4(const double M[4][4], double inv[4][4]) {
    double a[4][8];
    for (int i = 0; i < 4; ++i) {
        for (int j = 0; j < 4; ++j) { a[i][j] = M[i][j]; a[i][j + 4] = (i == j) ? 1.0 : 0.0; }
    }
    for (int col = 0; col < 4; ++col) {
        int piv = col;
        for (int r = col + 1; r < 4; ++r)
            if (fabs(a[r][col]) > fabs(a[piv][col])) piv = r;
        if (piv != col)
            for (int j = 0; j < 8; ++j) { double t = a[col][j]; a[col][j] = a[piv][j]; a[piv][j] = t; }
        double d = a[col][col];
        for (int j = 0; j < 8; ++j) a[col][j] /= d;
        for (int r = 0; r < 4; ++r) {
            if (r == col) continue;
            double f = a[r][col];
            for (int j = 0; j < 8; ++j) a[r][j] -= f * a[col][j];
        }
    }
    for (int i = 0; i < 4; ++i)
        for (int j = 0; j < 4; ++j) inv[i][j] = a[i][j + 4];
}

static SgCoef compute_coef() {
    SgCoef co;
    double A[WINDOW][4];
    for (int i = 0; i < WINDOW; ++i) {
        double p = (double)(i - HALF), v = 1.0;
        for (int j = 0; j < 4; ++j) { A[i][j] = v; v *= p; }
    }
    double N[4][4] = {};
    for (int i = 0; i < 4; ++i)
        for (int j = 0; j < 4; ++j) {
            double s = 0;
            for (int r = 0; r < WINDOW; ++r) s += A[r][i] * A[r][j];
            N[i][j] = s;
        }
    double Ninv[4][4];
    invert4(N, Ninv);
    for (int w = 0; w < WINDOW; ++w) {
        double s = 0;
        for (int j = 0; j < 4; ++j) s += Ninv[0][j] * A[w][j];
        co.c[w] = (float)s;
    }
    double V[WINDOW][4];
    for (int i = 0; i < WINDOW; ++i) {
        double p = (double)i, v = 1.0;
        for (int j = 0; j < 4; ++j) { V[i][j] = v; v *= p; }
    }
    double NV[4][4] = {};
    for (int i = 0; i < 4; ++i)
        for (int j = 0; j < 4; ++j) {
            double s = 0;
            for (int r = 0; r < WINDOW; ++r) s += V[r][i] * V[r][j];
            NV[i][j] = s;
        }
    double NVinv[4][4];
    invert4(NV, NVinv);
    for (int h = 0; h < HALF; ++h) {
        double T[4]; double v = 1.0;
        for (int j = 0; j < 4; ++j) { T[j] = v; v *= (double)h; }
        for (int w = 0; w < WINDOW; ++w) {
            double s = 0;
            for (int j = 0; j < 4; ++j) {
                double pv = 0;
                for (int m = 0; m < 4; ++m) pv += NVinv[j][m] * V[w][m];
                s += T[j] * pv;
            }
            co.E[h][w] = (float)s;
        }
    }
    return co;
}

// ---------------- kernel ---------------------------------------------------
// 93.1us structure (coalesced f32x4 nt staging -> LDS, stride-TPB scalar
// outputs, nt stores). Single change: TILE 2048 -> 4096 to halve per-element
// halo re-fetch, barrier-drain count, and staging-loop tail. Occupancy
// unchanged (LDS 16.5KB -> 9 blocks/CU by LDS, still wave-slot-capped at 8).

__global__ __launch_bounds__(TPB) void savgol_kernel(
    const float* __restrict__ x, float* __restrict__ out,
    SgCoef coef, int L, int tiles_per_row)
{
    __shared__ float lds[TILE + 16];   // covers [s-8, s+TILE+8)

    const int t    = threadIdx.x;
    const int tile = blockIdx.x;
    const int row  = blockIdx.y;
    const long long rowoff = (long long)row * (long long)L;
    const int s = tile * TILE;
    const float* __restrict__ xr  = x + rowoff;
    float* __restrict__       outr = out + rowoff;

    // Stage [s-8, s+TILE+8) into LDS with f32x4 nt loads (16B-aligned).
    const int NCHUNK = (TILE + 16) / 4;
    for (int chunk = t; chunk < NCHUNK; chunk += TPB) {
        int gbase = s - 8 + chunk * 4;
        f32x4 v;
        if (gbase >= 0 && gbase + 3 < L) {
            v = __builtin_nontemporal_load(
                    reinterpret_cast<const f32x4*>(xr + gbase));
        } else {
            #pragma unroll
            for (int q = 0; q < 4; ++q) {
                int g = gbase + q;
                v[q] = (g >= 0 && g < L) ? xr[g] : 0.0f;
            }
        }
        *reinterpret_cast<f32x4*>(&lds[chunk * 4]) = v;
    }
    __syncthreads();

    const bool first = (tile == 0);
    const bool last  = (tile == tiles_per_row - 1);

    #pragma unroll
    for (int j = 0; j < EPT; ++j) {
        const int nl = t + j * TPB;       // 0..TILE-1
        const int n  = s + nl;            // global output index in row
        // Interior FIR: out[n] = sum_k c[k] * x[n-5+k]; lds idx of x[n-5] = nl+3
        float acc = 0.0f;
        #pragma unroll
        for (int k = 0; k < WINDOW; ++k)
            acc = fmaf(coef.c[k], lds[nl + 3 + k], acc);
        float val = acc;
        if (first && nl < HALF) {
            // Left edge: out[h] = sum_w E[h][w] * x[w]; lds idx of x[w] = w+8
            float a = 0.0f;
            #pragma unroll
            for (int w = 0; w < WINDOW; ++w)
                a = fmaf(coef.E[nl][w], lds[w + 8], a);
            val = a;
        } else if (last && nl >= TILE - HALF) {
            // Right edge: h = L-1-n; out[n] = sum_w E[h][w] * x[L-1-w]
            int h = (L - 1) - n;          // 0..4
            float a = 0.0f;
            #pragma unroll
            for (int w = 0; w < WINDOW; ++w)
                a = fmaf(coef.E[h][w], lds[(TILE + 7) - w], a);  // (L-1-w)-(s-8), s=L-TILE
            val = a;
        }
        __builtin_nontemporal_store(val, &outr[n]);
    }
}

// ---------------- launch ---------------------------------------------------

extern "C" void kernel_launch(void* const* d_in, const int* in_sizes, int n_in,
                              void* d_out, int out_size, void* d_ws, size_t ws_size,
                              hipStream_t stream) {
    (void)d_ws; (void)ws_size; (void)n_in; (void)out_size;
    const float* x = (const float*)d_in[0];
    float* out = (float*)d_out;

    const int L = 65536;
    const int rows = in_sizes[0] / L;          // 64*16 = 1024
    const int tiles_per_row = L / TILE;        // 16

    SgCoef coef = compute_coef();

    dim3 grid(tiles_per_row, rows);
    dim3 block(TPB);
    savgol_kernel<<<grid, block, 0, stream>>>(x, out, coef, L, tiles_per_row);
}